// Round 4
// baseline (22889.102 us; speedup 1.0000x reference)
//
#include <hip/hip_runtime.h>
#include <stdint.h>
#include <stddef.h>

// LSTM_63488206569533: B=128, T=1024, I=256, H=512, fp32 in/out.
// Persistent kernel: 256 WGs (8 batch-groups x 32 unit-slices), one per CU.
// R6: XCD-local h exchange, HANG-PROOF version of R5.
//   Theory: R2/R3/R4 all measure ~8800 cy/step regardless of protocol ->
//   the cost is agent-scope (sc1/MALL) propagation latency (~1.5-2K cy RTT,
//   ~3 serial RTTs/step). bg=blockIdx&7 puts each group's 32 WGs on one XCD
//   (round-robin dispatch), whose shared L2 gives ~300 cy RTT via sc0 ops.
//   Safety ladder (no failure mode can hang or corrupt):
//   - XCD id via __builtin_amdgcn_s_getreg (no asm-parse risk); group enables
//     fast path only if all 32 members report the same id.
//   - DUAL STORE in fast mode: same word stored sc0 (local L2, fast same-XCD
//     visibility) AND agent/sc1 (MALL always current) -> agent loads always
//     make progress no matter what sc0 semantics turn out to be.
//   - All fast polls are BOUNDED (4096 rounds) with STICKY per-thread
//     escalation to proven agent loads.
//   - Non-fast groups run the R4 path verbatim (passed at 3867 us).

#define Bn   128
#define Tn   1024
#define In   256
#define Hn   512
#define PM   8     // batch groups
#define PN   32    // unit slices
#define BPW  16    // batches per WG
#define UPW  16    // units per WG
#define APAD 776   // padded A row length in bf16 elems (1552 B, 16B-aligned rows)
#define GPAD 17    // gate_lds padded row stride
#define FAST_SPIN 4096

typedef float f4 __attribute__((ext_vector_type(4)));
typedef short s8 __attribute__((ext_vector_type(8)));
typedef unsigned long long u64;

static __device__ __forceinline__ short f2bf(float f) {
  union { float f; unsigned u; } v; v.f = f;
  unsigned u = v.u;
  return (short)((u + 0x7FFFu + ((u >> 16) & 1u)) >> 16);  // RNE
}

// L2-coherent (bypass-L1) load, self-contained wait: safe because the
// consumer is data-dependent on the asm block's output (load+wait fused).
static __device__ __forceinline__ u64 ld_sc0_sync(const u64* p) {
  u64 v;
  asm volatile("global_load_dwordx2 %0, %1, off sc0\n\ts_waitcnt vmcnt(0)"
               : "=v"(v) : "v"(p) : "memory");
  return v;
}

__global__ __launch_bounds__(256, 1)
void lstm_persist(const float* __restrict__ x,
                  const float* __restrict__ W_ih,
                  const float* __restrict__ W_hh,
                  const float* __restrict__ b_ih,
                  const float* __restrict__ b_hh,
                  const float* __restrict__ fc_w,
                  const float* __restrict__ fc_b,
                  float* __restrict__ out,
                  unsigned* __restrict__ hw)   // [2][Bn][Hn] tagged dwords
{
  const int tid  = threadIdx.x;
  const int wave = tid >> 6;    // 0..3  == gate type (i,f,g,o)
  const int lane = tid & 63;
  const int n16  = lane & 15;   // MFMA: batch row (A) / gate col (B)
  const int q    = lane >> 4;   // MFMA quad -> k-subblock
  const int bg   = blockIdx.x & 7;   // batch group
  const int ns   = blockIdx.x >> 3;  // unit slice 0..31

  __shared__ short A_lds[16 * APAD];       // [batch 16][k 768(+pad)] bf16
  __shared__ float gate_lds[4 * 16 * GPAD];
  __shared__ int   fast_lds;

  // ---- registration: post my physical XCD id (agent scope = always correct).
  // s_getreg imm = ((size-1)<<11)|(offset<<6)|id ; HW_REG_XCC_ID id=20.
  // If the id were wrong we read junk -> ids disagree -> fallback (safe);
  // spurious agreement is ALSO safe (dual store + bounded escalation below).
  unsigned xcd = (unsigned)__builtin_amdgcn_s_getreg((31 << 11) | (0 << 6) | 20) & 0xFu;
  // Table = first 32 dwords of this group's parity-0 h block; first
  // overwritten (tag-2 h) only after every member passed registration-collect.
  unsigned* regtab = hw + (size_t)bg * (BPW * Hn);
  if (tid == 0)
    __hip_atomic_store(&regtab[ns], 0x100u | xcd, __ATOMIC_RELAXED, __HIP_MEMORY_SCOPE_AGENT);

  // ---- one-time: preload this wave's 16 W rows into B-fragments (bf16) ----
  s8 bfrag[24];
  {
    const int grow = wave * Hn + ns * UPW + n16;  // global gate row in [0,4H)
#pragma unroll
    for (int kk = 0; kk < 24; ++kk) {
      const float* p = (kk < 8)
        ? (W_ih + (size_t)grow * In + kk * 32 + q * 8)
        : (W_hh + (size_t)grow * Hn + (kk - 8) * 32 + q * 8);
      f4 lo = ((const f4*)p)[0];
      f4 hi = ((const f4*)p)[1];
      s8 b;
      b[0]=f2bf(lo[0]); b[1]=f2bf(lo[1]); b[2]=f2bf(lo[2]); b[3]=f2bf(lo[3]);
      b[4]=f2bf(hi[0]); b[5]=f2bf(hi[1]); b[6]=f2bf(hi[2]); b[7]=f2bf(hi[3]);
      bfrag[kk] = b;
    }
  }

  // ---- elementwise-phase mapping: tid -> (batch em, unit en) ----
  const int em  = tid >> 4;
  const int en  = tid & 15;
  const int ug  = ns * UPW + en;     // global unit
  const int bgl = bg * BPW + em;     // global batch
  const float bia = b_ih[ug]        + b_hh[ug];
  const float bfa = b_ih[Hn + ug]   + b_hh[Hn + ug];
  const float bga = b_ih[2*Hn + ug] + b_hh[2*Hn + ug];
  const float boa = b_ih[3*Hn + ug] + b_hh[3*Hn + ug];

  const float* xbase = x + (size_t)bgl * Tn * In + en * 16;
  const short* aptr  = A_lds + n16 * APAD + q * 8;
  const u64*   hw64  = (const u64*)hw;

  // ---- prologue: stage x(0) ----
  {
    const f4* xp = (const f4*)xbase;
    f4 a = xp[0], b = xp[1], c = xp[2], d = xp[3];
    s8 lo, hi;
    lo[0]=f2bf(a[0]); lo[1]=f2bf(a[1]); lo[2]=f2bf(a[2]); lo[3]=f2bf(a[3]);
    lo[4]=f2bf(b[0]); lo[5]=f2bf(b[1]); lo[6]=f2bf(b[2]); lo[7]=f2bf(b[3]);
    hi[0]=f2bf(c[0]); hi[1]=f2bf(c[1]); hi[2]=f2bf(c[2]); hi[3]=f2bf(c[3]);
    hi[4]=f2bf(d[0]); hi[5]=f2bf(d[1]); hi[6]=f2bf(d[2]); hi[7]=f2bf(d[3]);
    s8* dst = (s8*)(A_lds + em * APAD + en * 16);
    dst[0] = lo; dst[1] = hi;
  }

  // ---- collect peers' XCD ids; group is "fast" iff all 32 match ----
  if (tid < 64) {
    unsigned v;
    do {
      v = __hip_atomic_load(&regtab[tid & 31], __ATOMIC_RELAXED, __HIP_MEMORY_SCOPE_AGENT);
    } while (!(v & 0x100u));
    unsigned ref = (unsigned)__shfl((int)v, 0, 64);
    u64 same = __ballot(v == ref);
    if (tid == 0) fast_lds = (same == ~0ull) ? 1 : 0;
  }
  float creg = 0.f, hreg = 0.f;
  __syncthreads();
  const bool fastf = (fast_lds != 0);
  bool esc = false;   // sticky per-thread escalation to agent loads

  for (int t = 0; t < Tn; ++t) {
    u64 vals[16];
    const u64* pb = hw64 + ((t & 1) ? (Bn * Hn / 2) : 0) + bg * (BPW * Hn / 2) + tid;

    // (1) speculative bulk load (overlapped with x-MFMAs). Thread tid owns
    //     u64 j*256+tid: batch j, units 2tid,2tid+1 (producer = slice tid>>3).
    if (t > 0) {
      if (fastf && !esc) {
#pragma unroll
        for (int j = 0; j < 16; ++j)
          asm volatile("global_load_dwordx2 %0, %1, off sc0"
                       : "=v"(vals[j]) : "v"(pb + j * 256));
      } else {
#pragma unroll
        for (int j = 0; j < 16; ++j)
          vals[j] = __hip_atomic_load(pb + j * 256, __ATOMIC_RELAXED, __HIP_MEMORY_SCOPE_AGENT);
      }
    }

    // (2) prefetch x(t+1) into registers (consumed after barrier A)
    const int tn = (t + 1 < Tn) ? (t + 1) : t;
    const f4* xp = (const f4*)(xbase + (size_t)tn * In);
    f4 xa = xp[0], xb = xp[1], xc = xp[2], xd = xp[3];

    // (3) x-part MFMAs from A_lds while the loads are in flight
    f4 acc = {0.f, 0.f, 0.f, 0.f};
#pragma unroll
    for (int kk = 0; kk < 8; ++kk) {
      s8 a = *(const s8*)(aptr + kk * 32);
      acc = __builtin_amdgcn_mfma_f32_16x16x32_bf16(a, bfrag[kk], acc, 0, 0, 0);
    }

    if (t > 0) {
      const unsigned tt = (unsigned)t;
      const u64 WANT = ((u64)tt << 16) | ((u64)tt << 48);
      const u64 MASK = 0xFFFF0000FFFF0000ull;
      if (fastf && !esc) {
        asm volatile("s_waitcnt vmcnt(0)" ::: "memory");  // spec round landed
        __builtin_amdgcn_sched_barrier(0);
      }
      u64 bad = 0;
#pragma unroll
      for (int j = 0; j < 16; ++j) bad |= (vals[j] ^ WANT) & MASK;
      if (bad) {
        // (4) poll own j0 cheaply, then reload the stale remainder.
        int it = 0;
        u64 v0 = vals[0];
        while ((v0 ^ WANT) & MASK) {
          v0 = (fastf && !esc)
             ? ld_sc0_sync(pb)
             : __hip_atomic_load(pb, __ATOMIC_RELAXED, __HIP_MEMORY_SCOPE_AGENT);
          if (++it > FAST_SPIN) esc = true;   // sticky; agent path always progresses
        }
        vals[0] = v0;
        it = 0;
        for (;;) {
          u64 b2 = 0;
#pragma unroll
          for (int j = 1; j < 16; ++j) b2 |= (vals[j] ^ WANT) & MASK;
          if (b2 == 0) break;
          if (fastf && !esc) {
#pragma unroll
            for (int j = 1; j < 16; ++j)
              if ((vals[j] ^ WANT) & MASK)
                asm volatile("global_load_dwordx2 %0, %1, off sc0"
                             : "=v"(vals[j]) : "v"(pb + j * 256));
            asm volatile("s_waitcnt vmcnt(0)" ::: "memory");
            __builtin_amdgcn_sched_barrier(0);
          } else {
#pragma unroll
            for (int j = 1; j < 16; ++j)
              if ((vals[j] ^ WANT) & MASK)
                vals[j] = __hip_atomic_load(pb + j * 256, __ATOMIC_RELAXED, __HIP_MEMORY_SCOPE_AGENT);
          }
          if (++it > FAST_SPIN) esc = true;
        }
      }
      // (5) stage h -> A_lds[batch j][256 + 2tid]: dword addr j*388+128+tid
      //     -> conflict-free (2-way).
#pragma unroll
      for (int j = 0; j < 16; ++j) {
        unsigned w = (unsigned)(vals[j] & 0xFFFFu) | ((unsigned)(vals[j] >> 32) << 16);
        *(unsigned*)(A_lds + j * APAD + 256 + 2 * tid) = w;
      }
    }
    __syncthreads();   // (A) h staged; all x(t) LDS reads complete

    if (t > 0) {
      // (6) h-part MFMAs
#pragma unroll
      for (int kk = 8; kk < 24; ++kk) {
        s8 a = *(const s8*)(aptr + kk * 32);
        acc = __builtin_amdgcn_mfma_f32_16x16x32_bf16(a, bfrag[kk], acc, 0, 0, 0);
      }
    }

    // (7) stage x(t+1) -> A_lds (reads of x(t) finished before barrier A)
    {
      s8 lo, hi;
      lo[0]=f2bf(xa[0]); lo[1]=f2bf(xa[1]); lo[2]=f2bf(xa[2]); lo[3]=f2bf(xa[3]);
      lo[4]=f2bf(xb[0]); lo[5]=f2bf(xb[1]); lo[6]=f2bf(xb[2]); lo[7]=f2bf(xb[3]);
      hi[0]=f2bf(xc[0]); hi[1]=f2bf(xc[1]); hi[2]=f2bf(xc[2]); hi[3]=f2bf(xc[3]);
      hi[4]=f2bf(xd[0]); hi[5]=f2bf(xd[1]); hi[6]=f2bf(xd[2]); hi[7]=f2bf(xd[3]);
      s8* dst = (s8*)(A_lds + em * APAD + en * 16);
      dst[0] = lo; dst[1] = hi;
    }

    // (8) exchange gates through LDS (C-layout: row=(q*4+r)=batch, col=n16=unit)
#pragma unroll
    for (int r = 0; r < 4; ++r)
      gate_lds[wave * (16 * GPAD) + (q * 4 + r) * GPAD + n16] = acc[r];
    __syncthreads();   // (B) gates ready; x(t+1) staged

    // (9) per-(batch,unit) LSTM cell update; c stays in a register
    {
      float zi = gate_lds[0 * (16 * GPAD) + em * GPAD + en] + bia;
      float zf = gate_lds[1 * (16 * GPAD) + em * GPAD + en] + bfa;
      float zg = gate_lds[2 * (16 * GPAD) + em * GPAD + en] + bga;
      float zo = gate_lds[3 * (16 * GPAD) + em * GPAD + en] + boa;
      float gi = 1.f / (1.f + __expf(-zi));
      float gf = 1.f / (1.f + __expf(-zf));
      float gg = 2.f / (1.f + __expf(-2.f * zg)) - 1.f;   // tanh
      float go = 1.f / (1.f + __expf(-zo));
      creg = gf * creg + gi * gg;
      float tc = 2.f / (1.f + __expf(-2.f * creg)) - 1.f; // tanh(c)
      hreg = go * tc;
      // tagged store: (t+1)<<16 | bf16(h). Fast mode: DUAL store (sc0 for
      // same-XCD L2 visibility + agent/sc1 so MALL is always current for any
      // escalated/fallback reader). Same address, same value -> race-free.
      unsigned word = ((unsigned)(t + 1) << 16) | (unsigned)(unsigned short)f2bf(hreg);
      unsigned* hp = hw + (((t + 1) & 1) ? (Bn * Hn) : 0) + bgl * Hn + ug;
      if (fastf)
        asm volatile("global_store_dword %0, %1, off sc0" :: "v"(hp), "v"(word) : "memory");
      __hip_atomic_store(hp, word, __ATOMIC_RELAXED, __HIP_MEMORY_SCOPE_AGENT);
    }
    // no trailing barrier: next iteration's LDS writes are fenced by (A)/(B)
  }

  // ---- epilogue: out[b] = sum_u hT[b,u] * fc_w[u] + fc_b ----
  float partial = hreg * fc_w[ug];
#pragma unroll
  for (int off = 1; off < 16; off <<= 1)
    partial += __shfl_xor(partial, off, 64);   // reduce over the 16 units
  if (en == 0) {
    if (ns == 0) partial += fc_b[0];           // fc_b exactly once per batch
    atomicAdd(&out[bgl], partial);
  }
}

extern "C" void kernel_launch(void* const* d_in, const int* in_sizes, int n_in,
                              void* d_out, int out_size, void* d_ws, size_t ws_size,
                              hipStream_t stream) {
  const float* x    = (const float*)d_in[0];
  const float* W_ih = (const float*)d_in[1];
  const float* W_hh = (const float*)d_in[2];
  const float* b_ih = (const float*)d_in[3];
  const float* b_hh = (const float*)d_in[4];
  const float* fc_w = (const float*)d_in[5];
  const float* fc_b = (const float*)d_in[6];
  float* out = (float*)d_out;

  unsigned* hw = (unsigned*)d_ws;   // [2][Bn][Hn] tagged dwords = 512 KB

  // zero tags every launch (stale tags from a previous run would alias t);
  // also zeroes the in-band registration words.
  hipMemsetAsync(d_ws, 0, (size_t)2 * Bn * Hn * sizeof(unsigned), stream);
  hipMemsetAsync(d_out, 0, Bn * sizeof(float), stream);  // out via atomics

  lstm_persist<<<dim3(PM * PN), dim3(256), 0, stream>>>(
      x, W_ih, W_hh, b_ih, b_hh, fc_w, fc_b, out, hw);
}

// Round 5
// 6723.337 us; speedup vs baseline: 3.4044x; 3.4044x over previous
//
#include <hip/hip_runtime.h>
#include <stdint.h>
#include <stddef.h>

// LSTM_63488206569533: B=128, T=1024, I=256, H=512, fp32 in/out.
// Persistent kernel: 256 WGs (8 batch-groups x 32 unit-slices), one per CU.
// R7: VIRGIN-ADDRESS CACHEABLE h exchange.
//   Every protocol through agent-scope (MALL-only) ops costs ~8.5K cy/step
//   (R2/R3/R4 all ~3.7ms). Agent ops are needed only because a REUSED address
//   can serve stale cached data. Fix: step t's h lives in slot t%K (K = as
//   many 256KB slots as ws allows, up to T+1), tags (t+1) are unique across
//   the run -> a tag MATCH proves freshness even on a cached line, so
//   consumers may use PLAIN CACHEABLE loads (same-XCD L2 hit ~200cy, and the
//   32 WGs of a group share one XCD under round-robin dispatch).
//   Safety ladder (cannot hang, cannot corrupt):
//   - false positive: impossible (tags unique per run; ws memset per launch)
//   - false negative: plain polls bounded (512 rounds) -> sticky per-thread
//     escalation to the PROVEN R4 agent path; producers DUAL-store every h
//     word (plain for local L2 + agent/sc1 so MALL is always current), so
//     escalated readers always make progress. Worst case == R4 perf.

#define Bn   128
#define Tn   1024
#define In   256
#define Hn   512
#define PM   8     // batch groups
#define PN   32    // unit slices
#define BPW  16    // batches per WG
#define UPW  16    // units per WG
#define APAD 776   // padded A row length in bf16 elems (1552 B, 16B-aligned rows)
#define GPAD 17    // gate_lds padded row stride
#define FAST_SPIN 512

typedef float f4 __attribute__((ext_vector_type(4)));
typedef short s8 __attribute__((ext_vector_type(8)));
typedef unsigned long long u64;

static __device__ __forceinline__ short f2bf(float f) {
  union { float f; unsigned u; } v; v.f = f;
  unsigned u = v.u;
  return (short)((u + 0x7FFFu + ((u >> 16) & 1u)) >> 16);  // RNE
}

static __device__ __forceinline__ u64 ldv(const u64* p) {   // plain cacheable
  return *(volatile const u64*)p;
}

__global__ __launch_bounds__(256, 1)
void lstm_persist(const float* __restrict__ x,
                  const float* __restrict__ W_ih,
                  const float* __restrict__ W_hh,
                  const float* __restrict__ b_ih,
                  const float* __restrict__ b_hh,
                  const float* __restrict__ fc_w,
                  const float* __restrict__ fc_b,
                  float* __restrict__ out,
                  unsigned* __restrict__ hw,   // [K][Bn][Hn] tagged dwords
                  int K)                       // number of step slots (>=2)
{
  const int tid  = threadIdx.x;
  const int wave = tid >> 6;    // 0..3  == gate type (i,f,g,o)
  const int lane = tid & 63;
  const int n16  = lane & 15;   // MFMA: batch row (A) / gate col (B)
  const int q    = lane >> 4;   // MFMA quad -> k-subblock
  const int bg   = blockIdx.x & 7;   // batch group
  const int ns   = blockIdx.x >> 3;  // unit slice 0..31

  __shared__ short A_lds[16 * APAD];       // [batch 16][k 768(+pad)] bf16
  __shared__ float gate_lds[4 * 16 * GPAD];

  // ---- one-time: preload this wave's 16 W rows into B-fragments (bf16) ----
  s8 bfrag[24];
  {
    const int grow = wave * Hn + ns * UPW + n16;  // global gate row in [0,4H)
#pragma unroll
    for (int kk = 0; kk < 24; ++kk) {
      const float* p = (kk < 8)
        ? (W_ih + (size_t)grow * In + kk * 32 + q * 8)
        : (W_hh + (size_t)grow * Hn + (kk - 8) * 32 + q * 8);
      f4 lo = ((const f4*)p)[0];
      f4 hi = ((const f4*)p)[1];
      s8 b;
      b[0]=f2bf(lo[0]); b[1]=f2bf(lo[1]); b[2]=f2bf(lo[2]); b[3]=f2bf(lo[3]);
      b[4]=f2bf(hi[0]); b[5]=f2bf(hi[1]); b[6]=f2bf(hi[2]); b[7]=f2bf(hi[3]);
      bfrag[kk] = b;
    }
  }

  // ---- elementwise-phase mapping: tid -> (batch em, unit en) ----
  const int em  = tid >> 4;
  const int en  = tid & 15;
  const int ug  = ns * UPW + en;     // global unit
  const int bgl = bg * BPW + em;     // global batch
  const float bia = b_ih[ug]        + b_hh[ug];
  const float bfa = b_ih[Hn + ug]   + b_hh[Hn + ug];
  const float bga = b_ih[2*Hn + ug] + b_hh[2*Hn + ug];
  const float boa = b_ih[3*Hn + ug] + b_hh[3*Hn + ug];

  const float* xbase = x + (size_t)bgl * Tn * In + en * 16;
  const short* aptr  = A_lds + n16 * APAD + q * 8;
  const u64*   hw64  = (const u64*)hw;

  // ---- prologue: stage x(0) ----
  {
    const f4* xp = (const f4*)xbase;
    f4 a = xp[0], b = xp[1], c = xp[2], d = xp[3];
    s8 lo, hi;
    lo[0]=f2bf(a[0]); lo[1]=f2bf(a[1]); lo[2]=f2bf(a[2]); lo[3]=f2bf(a[3]);
    lo[4]=f2bf(b[0]); lo[5]=f2bf(b[1]); lo[6]=f2bf(b[2]); lo[7]=f2bf(b[3]);
    hi[0]=f2bf(c[0]); hi[1]=f2bf(c[1]); hi[2]=f2bf(c[2]); hi[3]=f2bf(c[3]);
    hi[4]=f2bf(d[0]); hi[5]=f2bf(d[1]); hi[6]=f2bf(d[2]); hi[7]=f2bf(d[3]);
    s8* dst = (s8*)(A_lds + em * APAD + en * 16);
    dst[0] = lo; dst[1] = hi;
  }

  float creg = 0.f, hreg = 0.f;
  bool esc = false;       // sticky per-thread escalation to agent loads
  int slot = 0, slotn = 1;  // slot of step t / step t+1
  __syncthreads();

  for (int t = 0; t < Tn; ++t) {
    u64 vals[16];
    // thread tid owns u64 j*256+tid of this group's [16][512] dword block:
    // batch j, units 2tid,2tid+1 (producer = slice tid>>3).
    const u64* pb = hw64 + (size_t)slot * (Bn * Hn / 2) + bg * (BPW * Hn / 2) + tid;

    // (1) speculative bulk load, overlapped with x-MFMAs
    if (t > 0) {
      if (!esc) {
#pragma unroll
        for (int j = 0; j < 16; ++j) vals[j] = ldv(pb + j * 256);
      } else {
#pragma unroll
        for (int j = 0; j < 16; ++j)
          vals[j] = __hip_atomic_load(pb + j * 256, __ATOMIC_RELAXED, __HIP_MEMORY_SCOPE_AGENT);
      }
    }

    // (2) prefetch x(t+1) into registers (consumed after barrier A)
    const int tn = (t + 1 < Tn) ? (t + 1) : t;
    const f4* xp = (const f4*)(xbase + (size_t)tn * In);
    f4 xa = xp[0], xb = xp[1], xc = xp[2], xd = xp[3];

    // (3) x-part MFMAs from A_lds while the loads are in flight
    f4 acc = {0.f, 0.f, 0.f, 0.f};
#pragma unroll
    for (int kk = 0; kk < 8; ++kk) {
      s8 a = *(const s8*)(aptr + kk * 32);
      acc = __builtin_amdgcn_mfma_f32_16x16x32_bf16(a, bfrag[kk], acc, 0, 0, 0);
    }

    if (t > 0) {
      const unsigned tt = (unsigned)t;
      const u64 WANT = ((u64)tt << 16) | ((u64)tt << 48);
      const u64 MASK = 0xFFFF0000FFFF0000ull;
      u64 bad = 0;
#pragma unroll
      for (int j = 0; j < 16; ++j) bad |= (vals[j] ^ WANT) & MASK;
      if (bad) {
        if (!esc) {
          // plain cacheable re-poll of stale words; bounded; sticky escalate
          int it = 0;
          for (;;) {
#pragma unroll
            for (int j = 0; j < 16; ++j)
              if ((vals[j] ^ WANT) & MASK) vals[j] = ldv(pb + j * 256);
            u64 b2 = 0;
#pragma unroll
            for (int j = 0; j < 16; ++j) b2 |= (vals[j] ^ WANT) & MASK;
            if (b2 == 0) break;
            if (++it > FAST_SPIN) { esc = true; break; }
          }
        }
        if (esc) {
          // PROVEN R4 agent path: poll own j0 cheaply, reload remainder.
          u64 v0 = vals[0];
          while ((v0 ^ WANT) & MASK)
            v0 = __hip_atomic_load(pb, __ATOMIC_RELAXED, __HIP_MEMORY_SCOPE_AGENT);
          vals[0] = v0;
          for (;;) {
            u64 b2 = 0;
#pragma unroll
            for (int j = 1; j < 16; ++j) b2 |= (vals[j] ^ WANT) & MASK;
            if (b2 == 0) break;
#pragma unroll
            for (int j = 1; j < 16; ++j)
              if ((vals[j] ^ WANT) & MASK)
                vals[j] = __hip_atomic_load(pb + j * 256, __ATOMIC_RELAXED, __HIP_MEMORY_SCOPE_AGENT);
          }
        }
      }
      // (5) stage h -> A_lds[batch j][256 + 2tid]: dword addr j*388+128+tid
      //     -> conflict-free (2-way).
#pragma unroll
      for (int j = 0; j < 16; ++j) {
        unsigned w = (unsigned)(vals[j] & 0xFFFFu) | ((unsigned)(vals[j] >> 32) << 16);
        *(unsigned*)(A_lds + j * APAD + 256 + 2 * tid) = w;
      }
    }
    __syncthreads();   // (A) h staged; all x(t) LDS reads complete

    if (t > 0) {
      // (6) h-part MFMAs
#pragma unroll
      for (int kk = 8; kk < 24; ++kk) {
        s8 a = *(const s8*)(aptr + kk * 32);
        acc = __builtin_amdgcn_mfma_f32_16x16x32_bf16(a, bfrag[kk], acc, 0, 0, 0);
      }
    }

    // (7) stage x(t+1) -> A_lds (reads of x(t) finished before barrier A)
    {
      s8 lo, hi;
      lo[0]=f2bf(xa[0]); lo[1]=f2bf(xa[1]); lo[2]=f2bf(xa[2]); lo[3]=f2bf(xa[3]);
      lo[4]=f2bf(xb[0]); lo[5]=f2bf(xb[1]); lo[6]=f2bf(xb[2]); lo[7]=f2bf(xb[3]);
      hi[0]=f2bf(xc[0]); hi[1]=f2bf(xc[1]); hi[2]=f2bf(xc[2]); hi[3]=f2bf(xc[3]);
      hi[4]=f2bf(xd[0]); hi[5]=f2bf(xd[1]); hi[6]=f2bf(xd[2]); hi[7]=f2bf(xd[3]);
      s8* dst = (s8*)(A_lds + em * APAD + en * 16);
      dst[0] = lo; dst[1] = hi;
    }

    // (8) exchange gates through LDS (C-layout: row=(q*4+r)=batch, col=n16=unit)
#pragma unroll
    for (int r = 0; r < 4; ++r)
      gate_lds[wave * (16 * GPAD) + (q * 4 + r) * GPAD + n16] = acc[r];
    __syncthreads();   // (B) gates ready; x(t+1) staged

    // (9) per-(batch,unit) LSTM cell update; c stays in a register
    {
      float zi = gate_lds[0 * (16 * GPAD) + em * GPAD + en] + bia;
      float zf = gate_lds[1 * (16 * GPAD) + em * GPAD + en] + bfa;
      float zg = gate_lds[2 * (16 * GPAD) + em * GPAD + en] + bga;
      float zo = gate_lds[3 * (16 * GPAD) + em * GPAD + en] + boa;
      float gi = 1.f / (1.f + __expf(-zi));
      float gf = 1.f / (1.f + __expf(-zf));
      float gg = 2.f / (1.f + __expf(-2.f * zg)) - 1.f;   // tanh
      float go = 1.f / (1.f + __expf(-zo));
      creg = gf * creg + gi * gg;
      float tc = 2.f / (1.f + __expf(-2.f * creg)) - 1.f; // tanh(c)
      hreg = go * tc;
      // tagged word (t+1)<<16 | bf16(h), DUAL store into slot slotn:
      // plain (local L2, fast same-XCD visibility) + agent/sc1 (MALL current
      // for any escalated reader). Same addr, same value -> race-free.
      unsigned word = ((unsigned)(t + 1) << 16) | (unsigned)(unsigned short)f2bf(hreg);
      unsigned* hp = hw + (size_t)slotn * (Bn * Hn) + bgl * Hn + ug;
      *(volatile unsigned*)hp = word;
      __hip_atomic_store(hp, word, __ATOMIC_RELAXED, __HIP_MEMORY_SCOPE_AGENT);
    }
    slot = slotn;
    slotn = (slotn + 1 == K) ? 0 : slotn + 1;
    // no trailing barrier: next iteration's LDS writes are fenced by (A)/(B)
  }

  // ---- epilogue: out[b] = sum_u hT[b,u] * fc_w[u] + fc_b ----
  float partial = hreg * fc_w[ug];
#pragma unroll
  for (int off = 1; off < 16; off <<= 1)
    partial += __shfl_xor(partial, off, 64);   // reduce over the 16 units
  if (en == 0) {
    if (ns == 0) partial += fc_b[0];           // fc_b exactly once per batch
    atomicAdd(&out[bgl], partial);
  }
}

extern "C" void kernel_launch(void* const* d_in, const int* in_sizes, int n_in,
                              void* d_out, int out_size, void* d_ws, size_t ws_size,
                              hipStream_t stream) {
  const float* x    = (const float*)d_in[0];
  const float* W_ih = (const float*)d_in[1];
  const float* W_hh = (const float*)d_in[2];
  const float* b_ih = (const float*)d_in[3];
  const float* b_hh = (const float*)d_in[4];
  const float* fc_w = (const float*)d_in[5];
  const float* fc_b = (const float*)d_in[6];
  float* out = (float*)d_out;

  // As many 256KB step-slots as the workspace allows (ideally T+1 = fully
  // virgin addressing; tags stay unique per run for ANY K >= 2).
  const size_t slot_bytes = (size_t)Bn * Hn * sizeof(unsigned);
  size_t cap = ws_size / slot_bytes;
  int K = (cap > (size_t)(Tn + 1)) ? (Tn + 1) : (int)cap;
  if (K < 2) K = 2;

  unsigned* hw = (unsigned*)d_ws;

  // zero all used slots each launch: tags from a previous launch at the same
  // addresses would alias (layout is deterministic) -> must be cleared.
  hipMemsetAsync(d_ws, 0, (size_t)K * slot_bytes, stream);
  hipMemsetAsync(d_out, 0, Bn * sizeof(float), stream);  // out via atomics

  lstm_persist<<<dim3(PM * PN), dim3(256), 0, stream>>>(
      x, W_ih, W_hh, b_ih, b_hh, fc_w, fc_b, out, hw, K);
}

// Round 7
// 6011.935 us; speedup vs baseline: 3.8073x; 1.1183x over previous
//
#include <hip/hip_runtime.h>
#include <stdint.h>
#include <stddef.h>

// LSTM_63488206569533: B=128, T=1024, I=256, H=512, fp32 in/out.
// Persistent kernel: 256 WGs (8 batch-groups x 32 unit-slices), one per CU.
// R9: back to the PROVEN agent-scope tagged-dataflow base (R4, passed), plus
//     three critical-path cuts that do not touch the exchange protocol:
//  1) RAW barriers (lgkmcnt(0)+s_barrier, no vmcnt drain): __syncthreads()
//     emits s_waitcnt vmcnt(0) before s_barrier, which stalls every thread
//     on the agent h-store ack (~1-2K cy) each step. The tag protocol never
//     needs the store drained; only LDS staging needs ordering.
//  2) gate_lds round trip removed: B-rows remapped to (4 units x 4 gates)
//     per wave; an in-wave 4-shuffle 4x4 transpose hands each lane all 4
//     gates of its (batch,unit). No cross-wave gate exchange at all.
//  3) 24-deep dependent MFMA chain split into 3 independent chains.
//     XCD/sc0 experiments (R5-R8) are abandoned: 4 attempts, 0 wins.

#define Bn   128
#define Tn   1024
#define In   256
#define Hn   512
#define PM   8     // batch groups
#define PN   32    // unit slices
#define BPW  16    // batches per WG
#define UPW  16    // units per WG
#define APAD 776   // padded A row length in bf16 elems (1552 B, 16B-aligned rows)

typedef float f4 __attribute__((ext_vector_type(4)));
typedef short s8 __attribute__((ext_vector_type(8)));
typedef unsigned long long u64;

// LDS-ordering barrier WITHOUT the vmcnt(0) drain __syncthreads would emit.
#define SBAR() do {                                        \
    __builtin_amdgcn_sched_barrier(0);                     \
    asm volatile("s_waitcnt lgkmcnt(0)" ::: "memory");     \
    __builtin_amdgcn_s_barrier();                          \
    __builtin_amdgcn_sched_barrier(0);                     \
  } while (0)

static __device__ __forceinline__ short f2bf(float f) {
  union { float f; unsigned u; } v; v.f = f;
  unsigned u = v.u;
  return (short)((u + 0x7FFFu + ((u >> 16) & 1u)) >> 16);  // RNE
}

__global__ __launch_bounds__(256, 1)
void lstm_persist(const float* __restrict__ x,
                  const float* __restrict__ W_ih,
                  const float* __restrict__ W_hh,
                  const float* __restrict__ b_ih,
                  const float* __restrict__ b_hh,
                  const float* __restrict__ fc_w,
                  const float* __restrict__ fc_b,
                  float* __restrict__ out,
                  unsigned* __restrict__ hw)   // [2][Bn][Hn] tagged dwords
{
  const int tid  = threadIdx.x;
  const int wave = tid >> 6;    // 0..3
  const int lane = tid & 63;
  const int n16  = lane & 15;   // MFMA: C col = B row
  const int q    = lane >> 4;   // MFMA quad -> batch block
  const int bg   = blockIdx.x & 7;   // batch group
  const int ns   = blockIdx.x >> 3;  // unit slice 0..31
  const int gEw  = n16 & 3;     // gate index of this lane's B-row
  const int uEw  = n16 >> 2;    // unit-within-wave of this lane's B-row

  __shared__ short A_lds[16 * APAD];   // [batch 16][k 768(+pad)] bf16

  // ---- one-time: preload this wave's 16 W rows into B-fragments (bf16).
  // Row n16 of wave w = (gate n16&3, unit ns*16 + w*4 + (n16>>2)).
  s8 bfrag[24];
  {
    const int grow = gEw * Hn + ns * UPW + wave * 4 + uEw;   // row in [0,4H)
#pragma unroll
    for (int kk = 0; kk < 24; ++kk) {
      const float* p = (kk < 8)
        ? (W_ih + (size_t)grow * In + kk * 32 + q * 8)
        : (W_hh + (size_t)grow * Hn + (kk - 8) * 32 + q * 8);
      f4 lo = ((const f4*)p)[0];
      f4 hi = ((const f4*)p)[1];
      s8 b;
      b[0]=f2bf(lo[0]); b[1]=f2bf(lo[1]); b[2]=f2bf(lo[2]); b[3]=f2bf(lo[3]);
      b[4]=f2bf(hi[0]); b[5]=f2bf(hi[1]); b[6]=f2bf(hi[2]); b[7]=f2bf(hi[3]);
      bfrag[kk] = b;
    }
  }

  // ---- staging mapping (data movement only): tid -> (batch em, unit en)
  const int em = tid >> 4;
  const int en = tid & 15;
  // ---- elementwise mapping (post-transpose): lane owns (bqE, ugE)
  const int ugE = ns * UPW + wave * 4 + uEw;   // global unit
  const int bqE = bg * BPW + q * 4 + gEw;      // global batch
  const float bi0 = b_ih[0*Hn + ugE] + b_hh[0*Hn + ugE];
  const float bi1 = b_ih[1*Hn + ugE] + b_hh[1*Hn + ugE];
  const float bi2 = b_ih[2*Hn + ugE] + b_hh[2*Hn + ugE];
  const float bi3 = b_ih[3*Hn + ugE] + b_hh[3*Hn + ugE];

  const float* xbase = x + (size_t)(bg * BPW + em) * Tn * In + en * 16;
  const short* aptr  = A_lds + n16 * APAD + q * 8;
  const u64*   hw64  = (const u64*)hw;

  // ---- prologue: stage x(0) ----
  {
    const f4* xp = (const f4*)xbase;
    f4 a = xp[0], b = xp[1], c = xp[2], d = xp[3];
    s8 lo, hi;
    lo[0]=f2bf(a[0]); lo[1]=f2bf(a[1]); lo[2]=f2bf(a[2]); lo[3]=f2bf(a[3]);
    lo[4]=f2bf(b[0]); lo[5]=f2bf(b[1]); lo[6]=f2bf(b[2]); lo[7]=f2bf(b[3]);
    hi[0]=f2bf(c[0]); hi[1]=f2bf(c[1]); hi[2]=f2bf(c[2]); hi[3]=f2bf(c[3]);
    hi[4]=f2bf(d[0]); hi[5]=f2bf(d[1]); hi[6]=f2bf(d[2]); hi[7]=f2bf(d[3]);
    s8* dst = (s8*)(A_lds + em * APAD + en * 16);
    dst[0] = lo; dst[1] = hi;
  }

  float creg = 0.f, hreg = 0.f;
  __syncthreads();   // once, full semantics

  for (int t = 0; t < Tn; ++t) {
    u64 vals[16];
    const u64* pb = hw64 + ((t & 1) ? (Bn * Hn / 2) : 0) + bg * (BPW * Hn / 2) + tid;

    // (1) speculative bulk load (PROVEN R4 path), overlapped with x-MFMAs.
    //     Thread tid owns u64 j*256+tid: batch j, units 2tid,2tid+1.
    if (t > 0) {
#pragma unroll
      for (int j = 0; j < 16; ++j)
        vals[j] = __hip_atomic_load(pb + j * 256, __ATOMIC_RELAXED, __HIP_MEMORY_SCOPE_AGENT);
    }

    // (2) prefetch x(t+1) into registers
    const int tn = (t + 1 < Tn) ? (t + 1) : t;
    const f4* xp = (const f4*)(xbase + (size_t)tn * In);
    f4 xa = xp[0], xb = xp[1], xc = xp[2], xd = xp[3];

    // (3) x-part MFMAs (chain 1 of 3)
    f4 accx = {0.f, 0.f, 0.f, 0.f};
#pragma unroll
    for (int kk = 0; kk < 8; ++kk) {
      s8 a = *(const s8*)(aptr + kk * 32);
      accx = __builtin_amdgcn_mfma_f32_16x16x32_bf16(a, bfrag[kk], accx, 0, 0, 0);
    }

    if (t > 0) {
      // (4) validate / poll (R4 verbatim: j0 cheap poll, then reload rest)
      const unsigned tt = (unsigned)t;
      const u64 WANT = ((u64)tt << 16) | ((u64)tt << 48);
      const u64 MASK = 0xFFFF0000FFFF0000ull;
      asm volatile("s_waitcnt vmcnt(0)" ::: "memory");
      __builtin_amdgcn_sched_barrier(0);
      u64 bad = 0;
#pragma unroll
      for (int j = 0; j < 16; ++j) bad |= (vals[j] ^ WANT) & MASK;
      if (bad) {
        u64 v0 = vals[0];
        while ((v0 ^ WANT) & MASK)
          v0 = __hip_atomic_load(pb, __ATOMIC_RELAXED, __HIP_MEMORY_SCOPE_AGENT);
        vals[0] = v0;
        for (;;) {
          u64 b2 = 0;
#pragma unroll
          for (int j = 1; j < 16; ++j) b2 |= (vals[j] ^ WANT) & MASK;
          if (b2 == 0) break;
#pragma unroll
          for (int j = 1; j < 16; ++j)
            if ((vals[j] ^ WANT) & MASK)
              vals[j] = __hip_atomic_load(pb + j * 256, __ATOMIC_RELAXED, __HIP_MEMORY_SCOPE_AGENT);
        }
      }
      // (5) stage h -> A_lds[batch j][256 + 2tid]: conflict-free (2-way)
#pragma unroll
      for (int j = 0; j < 16; ++j) {
        unsigned w = (unsigned)(vals[j] & 0xFFFFu) | ((unsigned)(vals[j] >> 32) << 16);
        *(unsigned*)(A_lds + j * APAD + 256 + 2 * tid) = w;
      }
    }
    SBAR();   // (A) h staged; x(t) LDS reads done. NO vmcnt drain.

    // (6) h-part MFMAs (chains 2 and 3)
    f4 h1 = {0.f, 0.f, 0.f, 0.f}, h2 = {0.f, 0.f, 0.f, 0.f};
    if (t > 0) {
#pragma unroll
      for (int kk = 8; kk < 16; ++kk) {
        s8 a = *(const s8*)(aptr + kk * 32);
        h1 = __builtin_amdgcn_mfma_f32_16x16x32_bf16(a, bfrag[kk], h1, 0, 0, 0);
      }
#pragma unroll
      for (int kk = 16; kk < 24; ++kk) {
        s8 a = *(const s8*)(aptr + kk * 32);
        h2 = __builtin_amdgcn_mfma_f32_16x16x32_bf16(a, bfrag[kk], h2, 0, 0, 0);
      }
    }

    // (7) in-wave 4x4 transpose within lane quads (swap lane bits<->reg bits):
    //     before: lane (q, 4u+g) reg r = (gate g, batch q*4+r)
    //     after : lane (q, 4u+g) reg r = (gate r, batch q*4+g)
    {
      float a0 = accx[0] + h1[0] + h2[0];
      float a1 = accx[1] + h1[1] + h2[1];
      float a2 = accx[2] + h1[2] + h2[2];
      float a3 = accx[3] + h1[3] + h2[3];
      float s0 = (gEw & 1) ? a0 : a1;
      float s1 = (gEw & 1) ? a2 : a3;
      float r0 = __shfl_xor(s0, 1, 64);
      float r1 = __shfl_xor(s1, 1, 64);
      float b0, b1, b2, b3;
      if (gEw & 1) { b0 = r0; b1 = a1; b2 = r1; b3 = a3; }
      else         { b0 = a0; b1 = r0; b2 = a2; b3 = r1; }
      float t0 = (gEw & 2) ? b0 : b2;
      float t1 = (gEw & 2) ? b1 : b3;
      float u0 = __shfl_xor(t0, 2, 64);
      float u1 = __shfl_xor(t1, 2, 64);
      float c0, c1, c2, c3;
      if (gEw & 2) { c0 = u0; c1 = u1; c2 = b2; c3 = b3; }
      else         { c0 = b0; c1 = b1; c2 = u0; c3 = u1; }

      // (8) LSTM cell update for this lane's (bqE, ugE); c in a register
      float zi = c0 + bi0, zf = c1 + bi1, zg = c2 + bi2, zo = c3 + bi3;
      float gi = 1.f / (1.f + __expf(-zi));
      float gf = 1.f / (1.f + __expf(-zf));
      float gg = 2.f / (1.f + __expf(-2.f * zg)) - 1.f;   // tanh
      float go = 1.f / (1.f + __expf(-zo));
      creg = gf * creg + gi * gg;
      float tc = 2.f / (1.f + __expf(-2.f * creg)) - 1.f; // tanh(c)
      hreg = go * tc;
      // fire-and-forget tagged store: (t+1)<<16 | bf16(h); drains in
      // background (bounded by next iteration's vmcnt(0) at tag check).
      unsigned word = ((unsigned)(t + 1) << 16) | (unsigned)(unsigned short)f2bf(hreg);
      unsigned* hp = hw + (((t + 1) & 1) ? (Bn * Hn) : 0) + (size_t)bqE * Hn + ugE;
      __hip_atomic_store(hp, word, __ATOMIC_RELAXED, __HIP_MEMORY_SCOPE_AGENT);
    }

    // (9) stage x(t+1) -> A_lds (x(t) reads finished before barrier A)
    {
      s8 lo, hi;
      lo[0]=f2bf(xa[0]); lo[1]=f2bf(xa[1]); lo[2]=f2bf(xa[2]); lo[3]=f2bf(xa[3]);
      lo[4]=f2bf(xb[0]); lo[5]=f2bf(xb[1]); lo[6]=f2bf(xb[2]); lo[7]=f2bf(xb[3]);
      hi[0]=f2bf(xc[0]); hi[1]=f2bf(xc[1]); hi[2]=f2bf(xc[2]); hi[3]=f2bf(xc[3]);
      hi[4]=f2bf(xd[0]); hi[5]=f2bf(xd[1]); hi[6]=f2bf(xd[2]); hi[7]=f2bf(xd[3]);
      s8* dst = (s8*)(A_lds + em * APAD + en * 16);
      dst[0] = lo; dst[1] = hi;
    }
    SBAR();   // (B) x(t+1) staged; h(t) reads done. NO vmcnt drain.
  }

  // ---- epilogue: out[b] = sum_u hT[b,u] * fc_w[u] + fc_b ----
  float partial = hreg * fc_w[ugE];
  partial += __shfl_xor(partial, 4, 64);   // reduce over uEw (this wave's 4 units)
  partial += __shfl_xor(partial, 8, 64);
  if (uEw == 0) {
    if (ns == 0 && wave == 0) partial += fc_b[0];   // fc_b exactly once per batch
    atomicAdd(&out[bqE], partial);
  }
}

extern "C" void kernel_launch(void* const* d_in, const int* in_sizes, int n_in,
                              void* d_out, int out_size, void* d_ws, size_t ws_size,
                              hipStream_t stream) {
  const float* x    = (const float*)d_in[0];
  const float* W_ih = (const float*)d_in[1];
  const float* W_hh = (const float*)d_in[2];
  const float* b_ih = (const float*)d_in[3];
  const float* b_hh = (const float*)d_in[4];
  const float* fc_w = (const float*)d_in[5];
  const float* fc_b = (const float*)d_in[6];
  float* out = (float*)d_out;

  unsigned* hw = (unsigned*)d_ws;   // [2][Bn][Hn] tagged dwords = 512 KB

  // zero tags every launch (stale tags from a previous run would alias t)
  hipMemsetAsync(d_ws, 0, (size_t)2 * Bn * Hn * sizeof(unsigned), stream);
  hipMemsetAsync(d_out, 0, Bn * sizeof(float), stream);  // out via atomics

  lstm_persist<<<dim3(PM * PN), dim3(256), 0, stream>>>(
      x, W_ih, W_hh, b_ih, b_hh, fc_w, fc_b, out, hw);
}

// Round 8
// 3849.239 us; speedup vs baseline: 5.9464x; 1.5619x over previous
//
#include <hip/hip_runtime.h>
#include <stdint.h>
#include <stddef.h>

// LSTM_63488206569533: B=128, T=1024, I=256, H=512, fp32 in/out.
// Persistent kernel: 256 WGs (8 batch-groups x 32 unit-slices), one per CU.
// R10: EXACT R4 base (passed, 3867us; store layout full-line coalesced) with
//      ONE mechanism changed: remove producer-side store-ack serialization.
//  (a) Loop barriers are lgkmcnt(0)+s_barrier only (no vmcnt drain).
//      __syncthreads() emits s_waitcnt vmcnt(0) which stalled every thread
//      ~1-2Kcy on the agent h-store ack at barrier B each step. The tag
//      protocol never needs the store drained; buffer-reuse safety needs
//      only the exec barrier (proof: passing barrier A at step t+1 implies
//      all 32 slices posted tag t+1, hence all finished consuming tag t).
//  (b) The tagged h-word is stored at the TOP of the NEXT iteration, AFTER
//      that iteration's 16 spec loads + 4 x-loads (sched_barrier-pinned).
//      vmcnt retires in issue order, so reading the spec loads no longer
//      waits on the (younger) store: the wave never stalls on its own ack.
//  R9's lane-scatter store regression is reverted (R4 layout kept verbatim).

#define Bn   128
#define Tn   1024
#define In   256
#define Hn   512
#define PM   8     // batch groups
#define PN   32    // unit slices
#define BPW  16    // batches per WG
#define UPW  16    // units per WG
#define APAD 776   // padded A row length in bf16 elems (1552 B, 16B-aligned rows)
#define GPAD 17    // gate_lds padded row stride

typedef float f4 __attribute__((ext_vector_type(4)));
typedef short s8 __attribute__((ext_vector_type(8)));
typedef unsigned long long u64;

// LDS-ordering barrier WITHOUT the vmcnt(0) drain __syncthreads would emit.
#define SBAR() do {                                        \
    __builtin_amdgcn_sched_barrier(0);                     \
    asm volatile("s_waitcnt lgkmcnt(0)" ::: "memory");     \
    __builtin_amdgcn_s_barrier();                          \
    __builtin_amdgcn_sched_barrier(0);                     \
  } while (0)

static __device__ __forceinline__ short f2bf(float f) {
  union { float f; unsigned u; } v; v.f = f;
  unsigned u = v.u;
  return (short)((u + 0x7FFFu + ((u >> 16) & 1u)) >> 16);  // RNE
}

__global__ __launch_bounds__(256, 1)
void lstm_persist(const float* __restrict__ x,
                  const float* __restrict__ W_ih,
                  const float* __restrict__ W_hh,
                  const float* __restrict__ b_ih,
                  const float* __restrict__ b_hh,
                  const float* __restrict__ fc_w,
                  const float* __restrict__ fc_b,
                  float* __restrict__ out,
                  unsigned* __restrict__ hw)   // [2][Bn][Hn] tagged dwords
{
  const int tid  = threadIdx.x;
  const int wave = tid >> 6;    // 0..3  == gate type (i,f,g,o)
  const int lane = tid & 63;
  const int n16  = lane & 15;   // MFMA: batch row (A) / gate col (B)
  const int q    = lane >> 4;   // MFMA quad -> k-subblock
  const int bg   = blockIdx.x & 7;   // batch group
  const int ns   = blockIdx.x >> 3;  // unit slice 0..31

  __shared__ short A_lds[16 * APAD];       // [batch 16][k 768(+pad)] bf16
  __shared__ float gate_lds[4 * 16 * GPAD];

  // ---- one-time: preload this wave's 16 W rows into B-fragments (bf16) ----
  s8 bfrag[24];
  {
    const int grow = wave * Hn + ns * UPW + n16;  // global gate row in [0,4H)
#pragma unroll
    for (int kk = 0; kk < 24; ++kk) {
      const float* p = (kk < 8)
        ? (W_ih + (size_t)grow * In + kk * 32 + q * 8)
        : (W_hh + (size_t)grow * Hn + (kk - 8) * 32 + q * 8);
      f4 lo = ((const f4*)p)[0];
      f4 hi = ((const f4*)p)[1];
      s8 b;
      b[0]=f2bf(lo[0]); b[1]=f2bf(lo[1]); b[2]=f2bf(lo[2]); b[3]=f2bf(lo[3]);
      b[4]=f2bf(hi[0]); b[5]=f2bf(hi[1]); b[6]=f2bf(hi[2]); b[7]=f2bf(hi[3]);
      bfrag[kk] = b;
    }
  }

  // ---- elementwise-phase mapping: tid -> (batch em, unit en) ----
  const int em  = tid >> 4;
  const int en  = tid & 15;
  const int ug  = ns * UPW + en;     // global unit
  const int bgl = bg * BPW + em;     // global batch
  const float bia = b_ih[ug]        + b_hh[ug];
  const float bfa = b_ih[Hn + ug]   + b_hh[Hn + ug];
  const float bga = b_ih[2*Hn + ug] + b_hh[2*Hn + ug];
  const float boa = b_ih[3*Hn + ug] + b_hh[3*Hn + ug];

  const float* xbase = x + (size_t)bgl * Tn * In + en * 16;
  const short* aptr  = A_lds + n16 * APAD + q * 8;
  const u64*   hw64  = (const u64*)hw;

  // ---- prologue: stage x(0) ----
  {
    const f4* xp = (const f4*)xbase;
    f4 a = xp[0], b = xp[1], c = xp[2], d = xp[3];
    s8 lo, hi;
    lo[0]=f2bf(a[0]); lo[1]=f2bf(a[1]); lo[2]=f2bf(a[2]); lo[3]=f2bf(a[3]);
    lo[4]=f2bf(b[0]); lo[5]=f2bf(b[1]); lo[6]=f2bf(b[2]); lo[7]=f2bf(b[3]);
    hi[0]=f2bf(c[0]); hi[1]=f2bf(c[1]); hi[2]=f2bf(c[2]); hi[3]=f2bf(c[3]);
    hi[4]=f2bf(d[0]); hi[5]=f2bf(d[1]); hi[6]=f2bf(d[2]); hi[7]=f2bf(d[3]);
    s8* dst = (s8*)(A_lds + em * APAD + en * 16);
    dst[0] = lo; dst[1] = hi;
  }

  float creg = 0.f, hreg = 0.f;
  unsigned pend = 0;            // tagged h-word produced at step t-1
  __syncthreads();              // once, full semantics

  for (int t = 0; t < Tn; ++t) {
    u64 vals[16];
    const u64* pb = hw64 + ((t & 1) ? (Bn * Hn / 2) : 0) + bg * (BPW * Hn / 2) + tid;

    // (1) speculative bulk load: thread tid owns u64 j*256+tid (batch j,
    //     units 2tid,2tid+1; producer = slice tid>>3).
    if (t > 0) {
#pragma unroll
      for (int j = 0; j < 16; ++j)
        vals[j] = __hip_atomic_load(pb + j * 256, __ATOMIC_RELAXED, __HIP_MEMORY_SCOPE_AGENT);
    }

    // (2) prefetch x(t+1) into registers (consumed after barrier A)
    const int tn = (t + 1 < Tn) ? (t + 1) : t;
    const f4* xp = (const f4*)(xbase + (size_t)tn * In);
    f4 xa = xp[0], xb = xp[1], xc = xp[2], xd = xp[3];

    // (2b) DEFERRED h-store: issue AFTER this iteration's loads so vmcnt's
    //      in-order retire never makes a load-use wait on the store's ack.
    //      Tag in pend is t, parity t&1 -> exactly what peers poll now.
    if (t > 0) {
      __builtin_amdgcn_sched_barrier(0);
      unsigned* hp = hw + ((t & 1) ? (Bn * Hn) : 0) + (size_t)bgl * Hn + ug;
      __hip_atomic_store(hp, pend, __ATOMIC_RELAXED, __HIP_MEMORY_SCOPE_AGENT);
      __builtin_amdgcn_sched_barrier(0);
    }

    // (3) x-part MFMAs from A_lds while the loads are in flight
    f4 acc = {0.f, 0.f, 0.f, 0.f};
#pragma unroll
    for (int kk = 0; kk < 8; ++kk) {
      s8 a = *(const s8*)(aptr + kk * 32);
      acc = __builtin_amdgcn_mfma_f32_16x16x32_bf16(a, bfrag[kk], acc, 0, 0, 0);
    }

    if (t > 0) {
      // (4) validate speculative round (compiler inserts the load waits);
      //     slow path: poll own j0 (8B/round), then reload stale remainder.
      const unsigned tt = (unsigned)t;
      const u64 WANT = ((u64)tt << 16) | ((u64)tt << 48);
      const u64 MASK = 0xFFFF0000FFFF0000ull;
      u64 bad = 0;
#pragma unroll
      for (int j = 0; j < 16; ++j) bad |= (vals[j] ^ WANT) & MASK;
      if (bad) {
        u64 v0 = vals[0];
        while ((v0 ^ WANT) & MASK)
          v0 = __hip_atomic_load(pb, __ATOMIC_RELAXED, __HIP_MEMORY_SCOPE_AGENT);
        vals[0] = v0;
        for (;;) {
          u64 b2 = 0;
#pragma unroll
          for (int j = 1; j < 16; ++j) b2 |= (vals[j] ^ WANT) & MASK;
          if (b2 == 0) break;
#pragma unroll
          for (int j = 1; j < 16; ++j)
            if ((vals[j] ^ WANT) & MASK)
              vals[j] = __hip_atomic_load(pb + j * 256, __ATOMIC_RELAXED, __HIP_MEMORY_SCOPE_AGENT);
        }
      }
      // (5) stage h -> A_lds[batch j][256 + 2tid]: dword addr j*388+128+tid
      //     -> conflict-free (2-way).
#pragma unroll
      for (int j = 0; j < 16; ++j) {
        unsigned w = (unsigned)(vals[j] & 0xFFFFu) | ((unsigned)(vals[j] >> 32) << 16);
        *(unsigned*)(A_lds + j * APAD + 256 + 2 * tid) = w;
      }
    }
    SBAR();   // (A) h staged; x(t) LDS reads done. No vmcnt drain.

    if (t > 0) {
      // (6) h-part MFMAs
#pragma unroll
      for (int kk = 8; kk < 24; ++kk) {
        s8 a = *(const s8*)(aptr + kk * 32);
        acc = __builtin_amdgcn_mfma_f32_16x16x32_bf16(a, bfrag[kk], acc, 0, 0, 0);
      }
    }

    // (7) stage x(t+1) -> A_lds (reads of x(t) finished before barrier A)
    {
      s8 lo, hi;
      lo[0]=f2bf(xa[0]); lo[1]=f2bf(xa[1]); lo[2]=f2bf(xa[2]); lo[3]=f2bf(xa[3]);
      lo[4]=f2bf(xb[0]); lo[5]=f2bf(xb[1]); lo[6]=f2bf(xb[2]); lo[7]=f2bf(xb[3]);
      hi[0]=f2bf(xc[0]); hi[1]=f2bf(xc[1]); hi[2]=f2bf(xc[2]); hi[3]=f2bf(xc[3]);
      hi[4]=f2bf(xd[0]); hi[5]=f2bf(xd[1]); hi[6]=f2bf(xd[2]); hi[7]=f2bf(xd[3]);
      s8* dst = (s8*)(A_lds + em * APAD + en * 16);
      dst[0] = lo; dst[1] = hi;
    }

    // (8) exchange gates through LDS (C-layout: row=(q*4+r)=batch, col=n16=unit)
#pragma unroll
    for (int r = 0; r < 4; ++r)
      gate_lds[wave * (16 * GPAD) + (q * 4 + r) * GPAD + n16] = acc[r];
    SBAR();   // (B) gates ready; x(t+1) staged. No vmcnt drain (the big one).

    // (9) per-(batch,unit) LSTM cell update; c stays in a register.
    //     The tagged store word is PREPARED here, ISSUED next iteration.
    {
      float zi = gate_lds[0 * (16 * GPAD) + em * GPAD + en] + bia;
      float zf = gate_lds[1 * (16 * GPAD) + em * GPAD + en] + bfa;
      float zg = gate_lds[2 * (16 * GPAD) + em * GPAD + en] + bga;
      float zo = gate_lds[3 * (16 * GPAD) + em * GPAD + en] + boa;
      float gi = 1.f / (1.f + __expf(-zi));
      float gf = 1.f / (1.f + __expf(-zf));
      float gg = 2.f / (1.f + __expf(-2.f * zg)) - 1.f;   // tanh
      float go = 1.f / (1.f + __expf(-zo));
      creg = gf * creg + gi * gg;
      float tc = 2.f / (1.f + __expf(-2.f * creg)) - 1.f; // tanh(c)
      hreg = go * tc;
      pend = ((unsigned)(t + 1) << 16) | (unsigned)(unsigned short)f2bf(hreg);
    }
    // (final pend, tag Tn, is never polled by anyone -> never stored)
  }

  // ---- epilogue: out[b] = sum_u hT[b,u] * fc_w[u] + fc_b ----
  float partial = hreg * fc_w[ug];
#pragma unroll
  for (int off = 1; off < 16; off <<= 1)
    partial += __shfl_xor(partial, off, 64);   // reduce over the 16 units
  if (en == 0) {
    if (ns == 0) partial += fc_b[0];           // fc_b exactly once per batch
    atomicAdd(&out[bgl], partial);
  }
}

extern "C" void kernel_launch(void* const* d_in, const int* in_sizes, int n_in,
                              void* d_out, int out_size, void* d_ws, size_t ws_size,
                              hipStream_t stream) {
  const float* x    = (const float*)d_in[0];
  const float* W_ih = (const float*)d_in[1];
  const float* W_hh = (const float*)d_in[2];
  const float* b_ih = (const float*)d_in[3];
  const float* b_hh = (const float*)d_in[4];
  const float* fc_w = (const float*)d_in[5];
  const float* fc_b = (const float*)d_in[6];
  float* out = (float*)d_out;

  unsigned* hw = (unsigned*)d_ws;   // [2][Bn][Hn] tagged dwords = 512 KB

  // zero tags every launch (stale tags from a previous run would alias t)
  hipMemsetAsync(d_ws, 0, (size_t)2 * Bn * Hn * sizeof(unsigned), stream);
  hipMemsetAsync(d_out, 0, Bn * sizeof(float), stream);  // out via atomics

  lstm_persist<<<dim3(PM * PN), dim3(256), 0, stream>>>(
      x, W_ih, W_hh, b_ih, b_hh, fc_w, fc_b, out, hw);
}

// Round 9
// 2504.539 us; speedup vs baseline: 9.1390x; 1.5369x over previous
//
#include <hip/hip_runtime.h>
#include <stdint.h>
#include <stddef.h>

// LSTM_63488206569533: B=128, T=1024, I=256, H=512, fp32 in/out.
// Persistent kernel: 256 WGs (8 batch-groups x 32 unit-slices), one per CU.
// R11: R2's volume-minimal exchange (packed bf16 h = 2B/unit, ack-then-flag)
//      -- the best measured protocol (3657us) -- with its three serial warts
//      removed:
//  1) 32 per-producer FLAG dwords polled in parallel by lanes 0-31 of every
//     wave (one coalesced 128B load/round) instead of 32 serialized
//     fetch_adds on ONE dword (+ tid0-only poll + s_sleep quantization).
//  2) APAD 776->792: row stride 388 dwords == 4 (mod 32) made the 24 MFMA
//     A-reads ~8-way bank conflicted (SQ_LDS_BANK_CONFLICT=1.34e8 == ~512
//     cy/WG-step). Stride 396 == 12 (mod 32) spreads to the inherent floor.
//  3) SBAR (lgkmcnt-only) for the two LDS barriers; the single full
//     __syncthreads() before the flag store stays (it orders every thread's
//     h-data stores before the flag -- R2's proven publication mechanism).

#define Bn   128
#define Tn   1024
#define In   256
#define Hn   512
#define PM   8     // batch groups
#define PN   32    // unit slices
#define BPW  16    // batches per WG
#define UPW  16    // units per WG
#define APAD 792   // padded A row len in bf16 (1584B; 396 dwords == 12 mod 32)
#define GPAD 17    // gate_lds padded row stride

typedef float f4 __attribute__((ext_vector_type(4)));
typedef short s8 __attribute__((ext_vector_type(8)));
typedef unsigned long long u64;

// LDS-ordering barrier WITHOUT the vmcnt(0) drain __syncthreads would emit.
#define SBAR() do {                                        \
    __builtin_amdgcn_sched_barrier(0);                     \
    asm volatile("s_waitcnt lgkmcnt(0)" ::: "memory");     \
    __builtin_amdgcn_s_barrier();                          \
    __builtin_amdgcn_sched_barrier(0);                     \
  } while (0)

static __device__ __forceinline__ short f2bf(float f) {
  union { float f; unsigned u; } v; v.f = f;
  unsigned u = v.u;
  return (short)((u + 0x7FFFu + ((u >> 16) & 1u)) >> 16);  // RNE
}

__global__ __launch_bounds__(256, 1)
void lstm_persist(const float* __restrict__ x,
                  const float* __restrict__ W_ih,
                  const float* __restrict__ W_hh,
                  const float* __restrict__ b_ih,
                  const float* __restrict__ b_hh,
                  const float* __restrict__ fc_w,
                  const float* __restrict__ fc_b,
                  float* __restrict__ out,
                  short* __restrict__ hbuf,      // [2][Bn][Hn] bf16 bits
                  unsigned* __restrict__ flags)  // [2][PM][PN] publication flags
{
  const int tid  = threadIdx.x;
  const int wave = tid >> 6;    // 0..3  == gate type (i,f,g,o)
  const int lane = tid & 63;
  const int n16  = lane & 15;   // MFMA: batch row (A) / gate col (B)
  const int q    = lane >> 4;   // MFMA quad -> k-subblock
  const int bg   = blockIdx.x & 7;   // batch group
  const int ns   = blockIdx.x >> 3;  // unit slice 0..31

  __shared__ short A_lds[16 * APAD];       // [batch 16][k 768(+pad)] bf16
  __shared__ float gate_lds[4 * 16 * GPAD];

  // ---- one-time: preload this wave's 16 W rows into B-fragments (bf16) ----
  s8 bfrag[24];
  {
    const int grow = wave * Hn + ns * UPW + n16;  // global gate row in [0,4H)
#pragma unroll
    for (int kk = 0; kk < 24; ++kk) {
      const float* p = (kk < 8)
        ? (W_ih + (size_t)grow * In + kk * 32 + q * 8)
        : (W_hh + (size_t)grow * Hn + (kk - 8) * 32 + q * 8);
      f4 lo = ((const f4*)p)[0];
      f4 hi = ((const f4*)p)[1];
      s8 b;
      b[0]=f2bf(lo[0]); b[1]=f2bf(lo[1]); b[2]=f2bf(lo[2]); b[3]=f2bf(lo[3]);
      b[4]=f2bf(hi[0]); b[5]=f2bf(hi[1]); b[6]=f2bf(hi[2]); b[7]=f2bf(hi[3]);
      bfrag[kk] = b;
    }
  }

  // ---- elementwise-phase mapping: tid -> (batch em, unit en) ----
  const int em  = tid >> 4;
  const int en  = tid & 15;
  const int ug  = ns * UPW + en;     // global unit
  const int bgl = bg * BPW + em;     // global batch
  const float bia = b_ih[ug]        + b_hh[ug];
  const float bfa = b_ih[Hn + ug]   + b_hh[Hn + ug];
  const float bga = b_ih[2*Hn + ug] + b_hh[2*Hn + ug];
  const float boa = b_ih[3*Hn + ug] + b_hh[3*Hn + ug];

  const float* xbase = x + (size_t)bgl * Tn * In + en * 16;
  const short* aptr  = A_lds + n16 * APAD + q * 8;
  const u64*   hb64  = (const u64*)hbuf;

  // ---- prologue: stage x(0) ----
  {
    const f4* xp = (const f4*)xbase;
    f4 a = xp[0], b = xp[1], c = xp[2], d = xp[3];
    s8 lo, hi;
    lo[0]=f2bf(a[0]); lo[1]=f2bf(a[1]); lo[2]=f2bf(a[2]); lo[3]=f2bf(a[3]);
    lo[4]=f2bf(b[0]); lo[5]=f2bf(b[1]); lo[6]=f2bf(b[2]); lo[7]=f2bf(b[3]);
    hi[0]=f2bf(c[0]); hi[1]=f2bf(c[1]); hi[2]=f2bf(c[2]); hi[3]=f2bf(c[3]);
    hi[4]=f2bf(d[0]); hi[5]=f2bf(d[1]); hi[6]=f2bf(d[2]); hi[7]=f2bf(d[3]);
    s8* dst = (s8*)(A_lds + em * APAD + en * 16);
    dst[0] = lo; dst[1] = hi;
  }

  float creg = 0.f, hreg = 0.f;
  __syncthreads();   // once, full semantics

  for (int t = 0; t < Tn; ++t) {
    // (1) prefetch x(t+1) into registers (consumed at step (7))
    const int tn = (t + 1 < Tn) ? (t + 1) : t;
    const f4* xp = (const f4*)(xbase + (size_t)tn * In);
    f4 xa = xp[0], xb = xp[1], xc = xp[2], xd = xp[3];

    // (2) x-part MFMAs from A_lds (overlaps flag propagation of peers)
    f4 acc = {0.f, 0.f, 0.f, 0.f};
#pragma unroll
    for (int kk = 0; kk < 8; ++kk) {
      s8 a = *(const s8*)(aptr + kk * 32);
      acc = __builtin_amdgcn_mfma_f32_16x16x32_bf16(a, bfrag[kk], acc, 0, 0, 0);
    }

    if (t > 0) {
      // (3) flag poll: lanes 0-31 of EVERY wave each own one producer flag
      //     (one coalesced 128B load per round). Own slice auto-passes.
      {
        const unsigned want = (unsigned)t;
        const unsigned* fb = flags + (t & 1) * (PM * PN) + bg * PN;
        const bool mine = (lane < 32) && (lane != ns);
        for (;;) {
          bool ok = true;
          if (mine) {
            unsigned fv = __hip_atomic_load(fb + lane, __ATOMIC_RELAXED,
                                            __HIP_MEMORY_SCOPE_AGENT);
            ok = (fv >= want);
          }
          if (__ballot(ok) == ~0ull) break;
        }
      }
      // (4) bulk h load (guaranteed fresh; flags follow data): 8 coalesced
      //     u64 loads/thread; u64 n = i*256+tid -> batch 2i+(tid>>7),
      //     units 4*(tid&127)..+3. Stage as one b64 per row (2-way, free).
      const u64* pb = hb64 + (size_t)(t & 1) * (Bn * Hn / 4) + bg * (BPW * Hn / 4) + tid;
      u64 vals[8];
#pragma unroll
      for (int i = 0; i < 8; ++i)
        vals[i] = __hip_atomic_load(pb + i * 256, __ATOMIC_RELAXED,
                                    __HIP_MEMORY_SCOPE_AGENT);
      const int rbase = (tid >> 7);
      const int cshort = 256 + 4 * (tid & 127);
#pragma unroll
      for (int i = 0; i < 8; ++i)
        *(u64*)(A_lds + (2 * i + rbase) * APAD + cshort) = vals[i];
    }
    SBAR();   // (A) h staged; x(t) LDS reads complete

    if (t > 0) {
      // (5) h-part MFMAs
#pragma unroll
      for (int kk = 8; kk < 24; ++kk) {
        s8 a = *(const s8*)(aptr + kk * 32);
        acc = __builtin_amdgcn_mfma_f32_16x16x32_bf16(a, bfrag[kk], acc, 0, 0, 0);
      }
    }

    // (7) stage x(t+1) -> A_lds cols [0,256) (x(t) reads done before (A))
    {
      s8 lo, hi;
      lo[0]=f2bf(xa[0]); lo[1]=f2bf(xa[1]); lo[2]=f2bf(xa[2]); lo[3]=f2bf(xa[3]);
      lo[4]=f2bf(xb[0]); lo[5]=f2bf(xb[1]); lo[6]=f2bf(xb[2]); lo[7]=f2bf(xb[3]);
      hi[0]=f2bf(xc[0]); hi[1]=f2bf(xc[1]); hi[2]=f2bf(xc[2]); hi[3]=f2bf(xc[3]);
      hi[4]=f2bf(xd[0]); hi[5]=f2bf(xd[1]); hi[6]=f2bf(xd[2]); hi[7]=f2bf(xd[3]);
      s8* dst = (s8*)(A_lds + em * APAD + en * 16);
      dst[0] = lo; dst[1] = hi;
    }

    // (8) exchange gates through LDS (C-layout: row=(q*4+r)=batch, col=n16=unit)
#pragma unroll
    for (int r = 0; r < 4; ++r)
      gate_lds[wave * (16 * GPAD) + (q * 4 + r) * GPAD + n16] = acc[r];
    SBAR();   // (B) gates ready; x(t+1) staged

    // (9) per-(batch,unit) LSTM cell update; c stays in a register
    {
      float zi = gate_lds[0 * (16 * GPAD) + em * GPAD + en] + bia;
      float zf = gate_lds[1 * (16 * GPAD) + em * GPAD + en] + bfa;
      float zg = gate_lds[2 * (16 * GPAD) + em * GPAD + en] + bga;
      float zo = gate_lds[3 * (16 * GPAD) + em * GPAD + en] + boa;
      float gi = 1.f / (1.f + __expf(-zi));
      float gf = 1.f / (1.f + __expf(-zf));
      float gg = 2.f / (1.f + __expf(-2.f * zg)) - 1.f;   // tanh
      float go = 1.f / (1.f + __expf(-zo));
      creg = gf * creg + gi * gg;
      float tc = 2.f / (1.f + __expf(-2.f * creg)) - 1.f; // tanh(c)
      hreg = go * tc;
    }

    if (t + 1 < Tn) {
      // (10) store h(t+1) packed bf16 (2 units/dword, R2's proven layout)
      unsigned hb = (unsigned short)f2bf(hreg);
      unsigned ob = (unsigned)__shfl_xor((int)hb, 1, 64);
      if (!(en & 1)) {
        unsigned packed = hb | (ob << 16);
        unsigned* hp = (unsigned*)hbuf + (size_t)((t + 1) & 1) * (Bn * Hn / 2)
                     + bgl * (Hn / 2) + ((unsigned)ug >> 1);
        __hip_atomic_store(hp, packed, __ATOMIC_RELAXED, __HIP_MEMORY_SCOPE_AGENT);
      }
      // (11) publication: drain every thread's data store, then ONE flag.
      __syncthreads();   // full semantics: s_waitcnt vmcnt(0) + s_barrier
      if (tid == 0)
        __hip_atomic_store(flags + ((t + 1) & 1) * (PM * PN) + bg * PN + ns,
                           (unsigned)(t + 1), __ATOMIC_RELAXED,
                           __HIP_MEMORY_SCOPE_AGENT);
    }
  }

  // ---- epilogue: out[b] = sum_u hT[b,u] * fc_w[u] + fc_b ----
  float partial = hreg * fc_w[ug];
#pragma unroll
  for (int off = 1; off < 16; off <<= 1)
    partial += __shfl_xor(partial, off, 64);   // reduce over the 16 units
  if (en == 0) {
    if (ns == 0) partial += fc_b[0];           // fc_b exactly once per batch
    atomicAdd(&out[bgl], partial);
  }
}

extern "C" void kernel_launch(void* const* d_in, const int* in_sizes, int n_in,
                              void* d_out, int out_size, void* d_ws, size_t ws_size,
                              hipStream_t stream) {
  const float* x    = (const float*)d_in[0];
  const float* W_ih = (const float*)d_in[1];
  const float* W_hh = (const float*)d_in[2];
  const float* b_ih = (const float*)d_in[3];
  const float* b_hh = (const float*)d_in[4];
  const float* fc_w = (const float*)d_in[5];
  const float* fc_b = (const float*)d_in[6];
  float* out = (float*)d_out;

  short*    hbuf  = (short*)d_ws;                          // 256 KB
  unsigned* flags = (unsigned*)((char*)d_ws + 262144);     // 2 KB

  // zero h + flags every launch (flag values are monotonic per run)
  hipMemsetAsync(d_ws, 0, 262144 + 2048, stream);
  hipMemsetAsync(d_out, 0, Bn * sizeof(float), stream);  // out via atomics

  lstm_persist<<<dim3(PM * PN), dim3(256), 0, stream>>>(
      x, W_ih, W_hh, b_ih, b_hh, fc_w, fc_b, out, hbuf, flags);
}